// Round 6
// baseline (473.795 us; speedup 1.0000x reference)
//
#include <hip/hip_runtime.h>
#include <hip/hip_bf16.h>
#include <math.h>

#define HIDDEN 2560
#define NH 32
#define NKV 8
#define HD 80
#define BATCH 2
#define SEQ 2048
#define QH_COLS (NH*HD)                  // 2560
#define KV_COLS (NKV*HD)                 // 640
#define QKV_COLS (QH_COLS + 2*KV_COLS)   // 3840 fused q|k|v row
#define ROWS (BATCH*SEQ)                 // 4096

typedef __attribute__((ext_vector_type(4))) float floatx4;
typedef __attribute__((ext_vector_type(16))) float floatx16;
typedef __attribute__((ext_vector_type(8))) short shortx8;
typedef __attribute__((ext_vector_type(4))) unsigned short u16x4;
typedef unsigned short u16;

__device__ inline u16 f2bf(float f) { __hip_bfloat16 h = __float2bfloat16(f); return *(u16*)&h; }
__device__ inline void storeC(float v, float* p) { *p = v; }
__device__ inline void storeC(float v, u16* p) { *p = f2bf(v); }

#if __has_builtin(__builtin_amdgcn_exp2f)
__device__ inline float fexp2(float x) { return __builtin_amdgcn_exp2f(x); }
#else
__device__ inline float fexp2(float x) { return __expf(x * 0.6931471805599453f); }
#endif

// packed f32x2 -> bf16x2 (low16 = first arg)
__device__ __forceinline__ unsigned cvtpk(float lo, float hi2) {
    unsigned r;
    asm("v_cvt_pk_bf16_f32 %0, %1, %2" : "=v"(r) : "v"(lo), "v"(hi2));
    return r;
}
// swap a.rows[32:63] <-> b.rows[0:31]
__device__ __forceinline__ void pl32swap(unsigned &a, unsigned &b) {
#if __has_builtin(__builtin_amdgcn_permlane32_swap)
    auto r = __builtin_amdgcn_permlane32_swap(a, b, false, false);
    a = r[0]; b = r[1];
#else
    asm("v_permlane32_swap_b32 %0, %1" : "+v"(a), "+v"(b));
#endif
}

#define GLL(gp, lp) __builtin_amdgcn_global_load_lds( \
    (const __attribute__((address_space(1))) unsigned int*)(gp), \
    (__attribute__((address_space(3))) unsigned int*)(lp), 16, 0, 0)

// ---------------- fp32 -> bf16 elementwise (x) ----------------
__global__ __launch_bounds__(256) void conv_bf16(const float* __restrict__ x,
                                                 u16* __restrict__ y) {
    int i = (blockIdx.x * 256 + threadIdx.x) * 4;
    float4 v = *(const float4*)(x + i);
    u16x4 o = { f2bf(v.x), f2bf(v.y), f2bf(v.z), f2bf(v.w) };
    *(u16x4*)(y + i) = o;
}

// ---------------- fp32 [K][N] -> bf16 [N][K] transpose-convert ----------------
__global__ __launch_bounds__(256) void transpose_conv(const float* __restrict__ W,
                                                      u16* __restrict__ Wt,
                                                      int K, int N) {
    __shared__ float tile[64][65];
    const int tid = threadIdx.x;
    const int n0 = blockIdx.x * 64, k0 = blockIdx.y * 64;
    const int r = tid >> 4, c4 = (tid & 15) * 4;
#pragma unroll
    for (int i = 0; i < 4; i++) {
        float4 v = *(const float4*)(W + (size_t)(k0 + r + i * 16) * N + n0 + c4);
        tile[r + i * 16][c4 + 0] = v.x;
        tile[r + i * 16][c4 + 1] = v.y;
        tile[r + i * 16][c4 + 2] = v.z;
        tile[r + i * 16][c4 + 3] = v.w;
    }
    __syncthreads();
    const int n = tid >> 2, kg = (tid & 3) * 16;
    __align__(16) u16 tmp[16];
#pragma unroll
    for (int j = 0; j < 16; j++) tmp[j] = f2bf(tile[kg + j][n]);
    u16* dst = Wt + (size_t)(n0 + n) * K + k0 + kg;
    *(uint4*)dst = *(const uint4*)tmp;
    *(uint4*)(dst + 8) = *(const uint4*)(tmp + 8);
}

// ---------------- 256x256 bf16 GEMM, 1-barrier-per-phase pipeline ----------------
// C[M,N] = A[M,K] @ Bt[N,K]^T.  512 threads = 8 waves (2M x 4N), 2 waves/SIMD;
// per-wave out 128x64 = acc[8][4] 16x16x32 frags.  BK=64, tiles in pairs
// (t0 -> buf0, t1 -> buf1), 8 phases/iteration.
// LDS 128 KB (u16): buf0 { A-kh0@0, A-kh1@8192, B-kh0@16384, B-kh1@24576 },
// buf1 same +32768.  Half-region = [kc:4][256 rows][8] -> conflict-free
// ds_read_b128 AND lane-linear GLL (0 conflicts measured r2/r4/r5).
// Phase p = [ds_reads(p); 2-GLL stage; vmcnt (even phases); s_barrier;
//            sched_barrier(0); setprio(1) 16 MFMA setprio(0)].
// MFMA(p) runs AFTER the barrier, in the same window as reads(p+1) ->
// matrix pipe and LDS pipe overlap across waves (r5 lesson: the 2-barrier
// lockstep alternated them at ~975 cyc/segment).
// WAR: stage(p) targets the region LAST READ at phase p-2; stage issues after
// bar(p-1) while those reads were serviced >=1 window earlier.  RAW: vmcnt(6)
// at even phases retires stages >=3 phases old (FIFO-traced incl. prologue &
// tail: last iteration 8/4/0); retired loads were issued >=2100 cyc earlier.
#define STAGE_HALF(MP, ROFF, T, KH) do { \
    GLL(MP + (T) * 64 + (KH) * 32 + skc * 8,       SM + (ROFF) + skc * 2048 + srow8); \
    GLL(MP + (T) * 64 + (KH) * 32 + (skc + 2) * 8, SM + (ROFF) + (skc + 2) * 2048 + srow8); \
} while (0)

#define VMCNT(N) asm volatile("s_waitcnt vmcnt(" #N ")" ::: "memory")
#define BARSB do { __builtin_amdgcn_s_barrier(); __builtin_amdgcn_sched_barrier(0); } while (0)

#define LOAD_B(BUFB, KH) do { const u16* _br = SM + (BUFB) + (KH) * 8192 + boff; \
    b0 = *(const shortx8*)(_br);        b1 = *(const shortx8*)(_br + 128); \
    b2 = *(const shortx8*)(_br + 256);  b3 = *(const shortx8*)(_br + 384); } while (0)
#define LOAD_A(BUFB, KH, IH) do { const u16* _ar = SM + (BUFB) + (KH) * 8192 + aoff + (IH) * 512; \
    a0 = *(const shortx8*)(_ar);        a1 = *(const shortx8*)(_ar + 128); \
    a2 = *(const shortx8*)(_ar + 256);  a3 = *(const shortx8*)(_ar + 384); } while (0)

#define MFMA16(IH) \
    __builtin_amdgcn_s_setprio(1); \
    acc[(IH)*4+0][0] = __builtin_amdgcn_mfma_f32_16x16x32_bf16(a0, b0, acc[(IH)*4+0][0], 0, 0, 0); \
    acc[(IH)*4+0][1] = __builtin_amdgcn_mfma_f32_16x16x32_bf16(a0, b1, acc[(IH)*4+0][1], 0, 0, 0); \
    acc[(IH)*4+0][2] = __builtin_amdgcn_mfma_f32_16x16x32_bf16(a0, b2, acc[(IH)*4+0][2], 0, 0, 0); \
    acc[(IH)*4+0][3] = __builtin_amdgcn_mfma_f32_16x16x32_bf16(a0, b3, acc[(IH)*4+0][3], 0, 0, 0); \
    acc[(IH)*4+1][0] = __builtin_amdgcn_mfma_f32_16x16x32_bf16(a1, b0, acc[(IH)*4+1][0], 0, 0, 0); \
    acc[(IH)*4+1][1] = __builtin_amdgcn_mfma_f32_16x16x32_bf16(a1, b1, acc[(IH)*4+1][1], 0, 0, 0); \
    acc[(IH)*4+1][2] = __builtin_amdgcn_mfma_f32_16x16x32_bf16(a1, b2, acc[(IH)*4+1][2], 0, 0, 0); \
    acc[(IH)*4+1][3] = __builtin_amdgcn_mfma_f32_16x16x32_bf16(a1, b3, acc[(IH)*4+1][3], 0, 0, 0); \
    acc[(IH)*4+2][0] = __builtin_amdgcn_mfma_f32_16x16x32_bf16(a2, b0, acc[(IH)*4+2][0], 0, 0, 0); \
    acc[(IH)*4+2][1] = __builtin_amdgcn_mfma_f32_16x16x32_bf16(a2, b1, acc[(IH)*4+2][1], 0, 0, 0); \
    acc[(IH)*4+2][2] = __builtin_amdgcn_mfma_f32_16x16x32_bf16(a2, b2, acc[(IH)*4+2][2], 0, 0, 0); \
    acc[(IH)*4+2][3] = __builtin_amdgcn_mfma_f32_16x16x32_bf16(a2, b3, acc[(IH)*4+2][3], 0, 0, 0); \
    acc[(IH)*4+3][0] = __builtin_amdgcn_mfma_f32_16x16x32_bf16(a3, b0, acc[(IH)*4+3][0], 0, 0, 0); \
    acc[(IH)*4+3][1] = __builtin_amdgcn_mfma_f32_16x16x32_bf16(a3, b1, acc[(IH)*4+3][1], 0, 0, 0); \
    acc[(IH)*4+3][2] = __builtin_amdgcn_mfma_f32_16x16x32_bf16(a3, b2, acc[(IH)*4+3][2], 0, 0, 0); \
    acc[(IH)*4+3][3] = __builtin_amdgcn_mfma_f32_16x16x32_bf16(a3, b3, acc[(IH)*4+3][3], 0, 0, 0); \
    __builtin_amdgcn_s_setprio(0);

template <typename OutT>
__global__ __launch_bounds__(512, 2) void gemm256(const u16* __restrict__ A,
                                                  const u16* __restrict__ Bt,
                                                  OutT* __restrict__ C,
                                                  int M, int N, int K,
                                                  int nbx) {
    __shared__ __align__(16) u16 SM[65536];
    const int tid = threadIdx.x;
    const int wave = tid >> 6, lane = tid & 63;
    const int m16 = lane & 15, quad = lane >> 4;
    const int wm = wave >> 2, wn = wave & 3;

    // XCD-aware bijective swizzle (nwg is a multiple of 8)
    const int nwg = nbx * (M >> 8);
    const int cpx = nwg >> 3;
    const int bid = (int)blockIdx.x;
    const int swzb = (bid & 7) * cpx + (bid >> 3);
    const int bm = (swzb / nbx) * 256, bn = (swzb % nbx) * 256;

    // staging: thread covers row srow, kc chunks {skc, skc+2} of a half-region
    const int srow = tid & 255, skc = tid >> 8;
    const int srow8 = srow * 8;
    const u16* pA = A  + (size_t)(bm + srow) * K;
    const u16* pB = Bt + (size_t)(bn + srow) * K;

    // fragment read offsets (u16): + BUFB + kh*8192 (+16384 for B) + frag*128
    const int aoff = quad * 2048 + (wm * 128 + m16) * 8;
    const int boff = 16384 + quad * 2048 + (wn * 64 + m16) * 8;

    floatx4 acc[8][4];
#pragma unroll
    for (int i = 0; i < 8; i++)
#pragma unroll
        for (int j = 0; j < 4; j++) acc[i][j] = (floatx4){0.f, 0.f, 0.f, 0.f};

    const int nkt = K >> 6;       // 40 (even)
    const int nit = nkt >> 1;

    // ---- prologue: A0,B0,A1,B1 of t0 (buf0); A0',B0' of t1 (buf1) ----
    STAGE_HALF(pA, 0,     0, 0);
    STAGE_HALF(pB, 16384, 0, 0);
    STAGE_HALF(pA, 8192,  0, 1);
    STAGE_HALF(pB, 24576, 0, 1);
    STAGE_HALF(pA, 32768, 1, 0);
    STAGE_HALF(pB, 49152, 1, 0);
    VMCNT(8);                       // A0,B0 of t0 landed
    __builtin_amdgcn_s_barrier();
    __builtin_amdgcn_sched_barrier(0);

    for (int it = 0; it < nit; ++it) {
        const int t0 = 2 * it, t1 = t0 + 1;
        const bool pf = (it + 1 < nit);
        shortx8 a0, a1, a2, a3, b0, b1, b2, b3;
        // ph1: read buf0-kh0-ih0 (+B); stage buf1 B-kh1 <- t1 (read ph7(n-1))
        LOAD_A(0, 0, 0); LOAD_B(0, 0);
        STAGE_HALF(pB, 57344, t1, 1);
        BARSB; MFMA16(0);
        // ph2: read buf0-kh0-ih1; stage buf1 A-kh1 <- t1 (read ph8(n-1))
        LOAD_A(0, 0, 1);
        STAGE_HALF(pA, 40960, t1, 1);
        if (pf) { VMCNT(6); } else { VMCNT(8); }
        BARSB; MFMA16(1);
        // ph3: read buf0-kh1-ih0 (+B); stage buf0 B-kh0 <- t0+2 (read ph1)
        LOAD_A(0, 1, 0); LOAD_B(0, 1);
        if (pf) STAGE_HALF(pB, 16384, t0 + 2, 0);
        BARSB; MFMA16(0);
        // ph4: read buf0-kh1-ih1; stage buf0 A-kh0 <- t0+2 (read ph2)
        LOAD_A(0, 1, 1);
        if (pf) { STAGE_HALF(pA, 0, t0 + 2, 0); VMCNT(6); } else { VMCNT(4); }
        BARSB; MFMA16(1);
        // ph5: read buf1-kh0-ih0 (+B); stage buf0 B-kh1 <- t0+2 (read ph3)
        LOAD_A(32768, 0, 0); LOAD_B(32768, 0);
        if (pf) STAGE_HALF(pB, 24576, t0 + 2, 1);
        BARSB; MFMA16(0);
        // ph6: read buf1-kh0-ih1; stage buf0 A-kh1 <- t0+2 (read ph4)
        LOAD_A(32768, 0, 1);
        if (pf) { STAGE_HALF(pA, 8192, t0 + 2, 1); VMCNT(6); } else { VMCNT(0); }
        BARSB; MFMA16(1);
        // ph7: read buf1-kh1-ih0 (+B); stage buf1 B-kh0 <- t1+2 (read ph5)
        LOAD_A(32768, 1, 0); LOAD_B(32768, 1);
        if (pf) STAGE_HALF(pB, 49152, t1 + 2, 0);
        BARSB; MFMA16(0);
        // ph8: read buf1-kh1-ih1; stage buf1 A-kh0 <- t1+2 (read ph6)
        LOAD_A(32768, 1, 1);
        if (pf) { STAGE_HALF(pA, 32768, t1 + 2, 0); VMCNT(6); }
        BARSB; MFMA16(1);
    }

#pragma unroll
    for (int i = 0; i < 8; i++)
#pragma unroll
        for (int j = 0; j < 4; j++)
#pragma unroll
            for (int p = 0; p < 4; p++) {
                int row = bm + wm * 128 + i * 16 + quad * 4 + p;
                int col = bn + wn * 64 + j * 16 + m16;
                storeC(acc[i][j][p], &C[(size_t)row * N + col]);
            }
}

// ---------------- RoPE, in place on fused qkv rows; Q pre-scaled ----------------
__global__ __launch_bounds__(256) void rope_bf16(__hip_bfloat16* __restrict__ qkv,
                                                 const float* __restrict__ cf,
                                                 const float* __restrict__ sf) {
    int idx = blockIdx.x * 256 + threadIdx.x;
    int d  = idx % 40;
    int t  = idx / 40;
    int hh = t % (NH + NKV);
    int g  = t / (NH + NKV);
    int s  = g & (SEQ - 1);
    float c1 = cf[s * HD + d],      s1 = sf[s * HD + d];
    float c2 = cf[s * HD + d + 40], s2 = sf[s * HD + d + 40];
    const float qsc = (hh < NH) ? (float)(0.11180339887498949 * 1.4426950408889634) : 1.0f;
    __hip_bfloat16* p = (hh < NH) ? (qkv + (size_t)g * QKV_COLS + hh * HD)
                                  : (qkv + (size_t)g * QKV_COLS + QH_COLS + (hh - NH) * HD);
    float x1 = __bfloat162float(p[d]);
    float x2 = __bfloat162float(p[d + 40]);
    p[d]      = __float2bfloat16((x1 * c1 - x2 * s1) * qsc);
    p[d + 40] = __float2bfloat16((x2 * c2 + x1 * s2) * qsc);
}

// ---------------- 32x32 MFMA flash attention, S^T formulation ----------------
__device__ __forceinline__ void stage_K(const u16* kg, u16* dst, int wave, int lane) {
#pragma unroll
    for (int t = 0; t < 2; t++) {
        int s = t * 256 + wave * 64 + lane;
        int db = t * 4 + wave;
        GLL(kg + (size_t)lane * QKV_COLS + db * 8, dst + s * 8);
    }
    if (wave < 2) {
        int s = 512 + wave * 64 + lane;
        int db = 8 + wave;
        GLL(kg + (size_t)lane * QKV_COLS + db * 8, dst + s * 8);
    }
}

__device__ __forceinline__ void load_V(const u16* vg, shortx8* vr, int wave, int lane) {
#pragma unroll
    for (int t = 0; t < 2; t++) {
        int db = t * 4 + wave;
        vr[t] = *(const shortx8*)(vg + (size_t)lane * QKV_COLS + db * 8);
    }
    if (wave < 2) vr[2] = *(const shortx8*)(vg + (size_t)lane * QKV_COLS + (8 + wave) * 8);
}

__device__ __forceinline__ void scatter_V(u16* Vs, const shortx8* vr, int wave, int lane) {
    const int kc = lane >> 3, jj = lane & 7;
    u16* base = Vs + kc * 768 + jj;
#pragma unroll
    for (int t = 0; t < 2; t++) {
        int db = t * 4 + wave;
#pragma unroll
        for (int i = 0; i < 8; i++) base[db * 64 + ((i ^ kc) << 3)] = vr[t][i];
    }
    if (wave < 2) {
        int db = 8 + wave;
#pragma unroll
        for (int i = 0; i < 8; i++) base[db * 64 + ((i ^ kc) << 3)] = vr[2][i];
    }
}

__global__ __launch_bounds__(256, 3) void attn_mfma(const u16* __restrict__ qkv,
                                                    u16* __restrict__ ob) {
    __shared__ __align__(16) u16 SM[16384];    // 32 KB
    u16* Kbuf = SM;            // 2 x 5120 u16; also Q staging [128][80] in prologue
    u16* Vs   = SM + 10240;    // 6144 u16 = [8][96][8]

    const int tid  = threadIdx.x;
    const int wave = tid >> 6;
    const int lane = tid & 63;
    const int l31  = lane & 31;
    const int hi   = lane >> 5;

    const int idx = blockIdx.x;                // 1D grid, LPT: qt=15 blocks first
    const int qt  = 15 - (idx >> 6);
    const int hb  = idx & 63;
    const int h   = hb >> 1;
    const int b   = hb & 1;
    const int kvh = h >> 2;
    const int qb  = qt * 128 + wave * 32;      // wave's first query row

    const u16* qgb = qkv + (size_t)(b * SEQ + qt * 128) * QKV_COLS + h * HD;
    const u16* kg0 = qkv + (size_t)(b * SEQ) * QKV_COLS + QH_COLS + kvh * HD;
    const u16* vg0 = qkv + (size_t)(b * SEQ) * QKV_COLS + QH_COLS + KV_COLS + kvh * HD;

    // zero V pad rows (d 80..95 of each kc chunk) -- disjoint from Q staging
    {
        int kc = tid >> 5, o = (tid & 31) * 4;
        *(u16x4*)(Vs + kc * 768 + 640 + o) = (u16x4){0, 0, 0, 0};
    }

    // ---- prologue: stage Q -> SM linear [128][80], read frags to regs ----
#pragma unroll
    for (int t = 0; t < 5; t++) {
        int s = t * 256 + tid;
        int row = s / 10, ch = s % 10;
        GLL(qgb + (size_t)row * QKV_COLS + ch * 8, SM + s * 8);
    }
    __syncthreads();
    shortx8 qf[5];
    {
        const u16* qrow = SM + (wave * 32 + l31) * 80 + hi * 8;
#pragma unroll
        for (int c = 0; c < 5; c++) qf[c] = *(const shortx8*)(qrow + c * 16);
    }
    __syncthreads();   // all waves' Q reads done; SM free for K

    // per-lane PV read bases: V_sub[kc8=2c+hi][(n*32+l31)^kc8][.]
    int vbase[4];
#pragma unroll
    for (int c = 0; c < 4; c++) {
        int k8 = c * 2 + hi;
        vbase[c] = k8 * 768 + ((l31 & 24) + ((l31 & 7) ^ k8)) * 8;
    }
    const u16* kfp = Kbuf + hi * 512 + l31 * 8;   // + cur*5120 + c*1024 + kr*256

    // ---- stage K0 (direct->LDS) and V0 (regs, then scatter) ----
    stage_K(kg0, Kbuf, wave, lane);
    shortx8 vr[3];
    load_V(vg0, vr, wave, lane);
    __syncthreads();                 // K0 in LDS (barrier drains vmcnt)
    scatter_V(Vs, vr, wave, lane);
    __syncthreads();                 // V0 visible

    floatx16 Oacc[3];
#pragma unroll
    for (int n = 0; n < 3; n++)
#pragma unroll
        for (int r = 0; r < 16; r++) Oacc[n][r] = 0.0f;
    float mrow = -1.0e30f, lrow = 0.0f;
    int cur = 0;
    const int nkt = 2 * qt + 2;

    for (int kt = 0; kt < nkt; kt++) {
        const bool last = (kt == nkt - 1);
        if (!last) {   // prefetch kt+1: K direct into other buffer, V into regs
            const u16* kg = kg0 + (size_t)(kt + 1) * 64 * QKV_COLS;
            const u16* vg = vg0 + (size_t)(kt + 1) * 64 * QKV_COLS;
            stage_K(kg, Kbuf + (cur ^ 1) * 5120, wave, lane);
            load_V(vg, vr, wave, lane);
        }

        const bool active = (kt * 64 <= qb + 31);
        if (active) {
            const u16* kp = kfp + cur * 5120;
            const bool kr1   = (kt * 64 + 32 <= qb + 31);
            const bool dmask = (kt * 64 + 63 > qb);
            // S^T = K.Q^T : D[key][query], col = query = l31
            floatx16 S0, S1;
            {
                floatx16 s;
#pragma unroll
                for (int r = 0; r < 16; r++) s[r] = 0.0f;
#pragma unroll
                for (int c = 0; c < 5; c++) {
                    shortx8 kf = *(const shortx8*)(kp + c * 1024);
                    s = __builtin_amdgcn_mfma_f32_32x32x16_bf16(kf, qf[c], s, 0, 0, 0);
                }
                S0 = s;
            }
            if (kr1) {
                floatx16 s;
#pragma unroll
                for (int r = 0; r < 16; r++) s[r] = 0.0f;
#pragma unroll
                for (int c = 0; c < 5; c++) {
                    shortx8 kf = *(const shortx8*)(kp + c * 1024 + 256);
                    s = __builtin_amdgcn_mfma_f32_32x32x16_bf16(kf, qf[c], s, 0, 0, 0);
                }
                S1 = s;
            }
            const int qrel = qb + l31 - kt * 64;
            if (dmask) {
#pragma unroll
                for (int r = 0; r < 16; r++) {
                    int rr = (r & 3) + 8 * (r >> 2) + 4 * hi;
                    if (rr > qrel) S0[r] = -1.0e30f;
                    if (kr1 && (32 + rr) > qrel) S1[r] = -1.0e30f;
                }
            }
            // online softmax (log2 domain), defer-max THR=8
            float mx = mrow;
#pragma unroll
            for (int r = 0; r < 16; r++) mx = fmaxf(mx, S0[r]);
            if (kr1) {
#pragma unroll
                for (int r = 0; r < 16; r++) mx = fmaxf(mx, S1[r]);
            }
            mx = fmaxf(mx, __shfl_xor(mx, 32));
            if (!__all(mx - mrow <= 8.0f)) {
                float alpha = fexp2(mrow - mx);
                lrow *= alpha;
#pragma unroll
                for (int n = 0; n < 3; n++)
#pragma unroll
                    for (int r = 0; r < 16; r++) Oacc[n][r] *= alpha;
                mrow = mx;
            }
            float rsum = 0.0f;
#pragma unroll
            for (int r = 0; r < 16; r++) { float p = fexp2(S0[r] - mrow); rsum += p; S0[r] = p; }
            if (kr1) {
#pragma unroll
                for (int r = 0; r < 16; r++) { float p = fexp2(S1[r] - mrow); rsum += p; S1[r] = p; }
            }
            rsum += __shfl_xor(rsum, 32);
            lrow += rsum;

            // P -> bf16 B-frags in-register; O^T += V^T.P
#pragma unroll
            for (int kr = 0; kr < 2; kr++) {
                if (kr == 1 && !kr1) break;
                floatx16& Sv = (kr == 0) ? S0 : S1;
                unsigned d0[4], d1[4];
#pragma unroll
                for (int m = 0; m < 4; m++) {
                    d0[m] = cvtpk(Sv[4 * m + 0], Sv[4 * m + 1]);
                    d1[m] = cvtpk(Sv[4 * m + 2], Sv[4 * m + 3]);
                }
#pragma unroll
                for (int cb = 0; cb < 2; cb++) {
                    int c = kr * 2 + cb;
                    if (kt * 64 + c * 16 > qb + 31) break;
                    unsigned x0 = d0[2 * cb], y0 = d0[2 * cb + 1];
                    unsigned x1 = d1[2 * cb], y1 = d1[2 * cb + 1];
                    pl32swap(x0, y0);
                    pl32swap(x1, y1);
                    union { unsigned u[4]; shortx8 s8; } pf;
                    pf.u[0] = x0; pf.u[1] = x1; pf.u[2] = y0; pf.u[3] = y1;
#pragma unroll
                    for (int n = 0; n < 3; n++) {
                        shortx8 vf = *(const shortx8*)(Vs + vbase[c] + n * 256);
                        Oacc[n] = __builtin_amdgcn_mfma_f32_32x32x16_bf16(vf, pf.s8, Oacc[n], 0, 0, 0);
                    }
                }
            }
        }

        if (last) break;
        __syncthreads();               // all waves done with Vs & Kbuf[cur]; drains kr/vr vmcnt
        scatter_V(Vs, vr, wave, lane); // write V(kt+1)
        cur ^= 1;
        __syncthreads();               // Vs ready
    }

    // epilogue: O[q][d] from O^T tiles; d = n*32 + 8m + 4hi + p
    const float invl = 1.0f / lrow;
    u16* op = ob + (size_t)(b * SEQ + qt * 128 + wave * 32 + l31) * QH_COLS + h * HD + 4 * hi;
#pragma unroll
    for (int n = 0; n < 3; n++) {
        const int mmax = (n == 2) ? 2 : 4;
#pragma unroll
        for (int m = 0; m < mmax; m++) {
            u16x4 o4 = { f2bf(Oacc[n][4 * m + 0] * invl), f2bf(Oacc[n][4 * m + 1] * invl),
                         f2bf(Oacc[n][4 * m + 2] * invl), f2bf(Oacc[n][4 * m + 3] * invl) };
            *(u16x4*)(op + n * 32 + 8 * m) = o4;
        }
    }
}

// ---------------- launch ----------------
extern "C" void kernel_launch(void* const* d_in, const int* in_sizes, int n_in,
                              void* d_out, int out_size, void* d_ws, size_t ws_size,
                              hipStream_t stream) {
    const float* x    = (const float*)d_in[0];
    const float* cf   = (const float*)d_in[1];
    const float* sf   = (const float*)d_in[2];
    const float* Wq   = (const float*)d_in[3];
    const float* Wk   = (const float*)d_in[4];
    const float* Wv   = (const float*)d_in[5];
    const float* Wo   = (const float*)d_in[6];
    float* out = (float*)d_out;

    u16* xh    = (u16*)d_ws;                            // 4096x2560; later reused as obh
    u16* Wqkvt = xh    + (size_t)ROWS * HIDDEN;         // 3840x2560 (fused q|k|v weightsT)
    u16* Wot   = Wqkvt + (size_t)QKV_COLS * HIDDEN;     // 2560x2560
    u16* qkv   = Wot   + (size_t)QH_COLS * HIDDEN;      // 4096x3840 fused
    u16* obh   = xh;                                    // alias: x dead after projections

    dim3 blk(256);
    conv_bf16<<<(ROWS * HIDDEN / 4) / 256, blk, 0, stream>>>(x, xh);
    transpose_conv<<<dim3(QH_COLS / 64, HIDDEN / 64), blk, 0, stream>>>(Wq, Wqkvt, HIDDEN, QH_COLS);
    transpose_conv<<<dim3(KV_COLS / 64, HIDDEN / 64), blk, 0, stream>>>(Wk, Wqkvt + (size_t)QH_COLS * HIDDEN, HIDDEN, KV_COLS);
    transpose_conv<<<dim3(KV_COLS / 64, HIDDEN / 64), blk, 0, stream>>>(Wv, Wqkvt + (size_t)(QH_COLS + KV_COLS) * HIDDEN, HIDDEN, KV_COLS);
    transpose_conv<<<dim3(HIDDEN / 64, QH_COLS / 64), blk, 0, stream>>>(Wo, Wot, QH_COLS, HIDDEN);

    gemm256<u16><<<dim3((QKV_COLS / 256) * (ROWS / 256)), dim3(512), 0, stream>>>(xh, Wqkvt, qkv, ROWS, QKV_COLS, HIDDEN, QKV_COLS / 256);

    rope_bf16<<<(ROWS * (NH + NKV) * 40) / 256, blk, 0, stream>>>((__hip_bfloat16*)qkv, cf, sf);
    attn_mfma<<<dim3(16 * 64), blk, 0, stream>>>(qkv, obh);

    gemm256<float><<<dim3((HIDDEN / 256) * (ROWS / 256)), dim3(512), 0, stream>>>(obh, Wot, out, ROWS, HIDDEN, QH_COLS, HIDDEN / 256);
}

// Round 7
// 456.373 us; speedup vs baseline: 1.0382x; 1.0382x over previous
//
#include <hip/hip_runtime.h>
#include <hip/hip_bf16.h>
#include <math.h>

#define HIDDEN 2560
#define NH 32
#define NKV 8
#define HD 80
#define BATCH 2
#define SEQ 2048
#define QH_COLS (NH*HD)                  // 2560
#define KV_COLS (NKV*HD)                 // 640
#define QKV_COLS (QH_COLS + 2*KV_COLS)   // 3840 fused q|k|v row
#define ROWS (BATCH*SEQ)                 // 4096

typedef __attribute__((ext_vector_type(4))) float floatx4;
typedef __attribute__((ext_vector_type(16))) float floatx16;
typedef __attribute__((ext_vector_type(8))) short shortx8;
typedef __attribute__((ext_vector_type(4))) unsigned short u16x4;
typedef unsigned short u16;

__device__ inline u16 f2bf(float f) { __hip_bfloat16 h = __float2bfloat16(f); return *(u16*)&h; }
__device__ inline void storeC(float v, float* p) { *p = v; }
__device__ inline void storeC(float v, u16* p) { *p = f2bf(v); }

#if __has_builtin(__builtin_amdgcn_exp2f)
__device__ inline float fexp2(float x) { return __builtin_amdgcn_exp2f(x); }
#else
__device__ inline float fexp2(float x) { return __expf(x * 0.6931471805599453f); }
#endif

// packed f32x2 -> bf16x2 (low16 = first arg)
__device__ __forceinline__ unsigned cvtpk(float lo, float hi2) {
    unsigned r;
    asm("v_cvt_pk_bf16_f32 %0, %1, %2" : "=v"(r) : "v"(lo), "v"(hi2));
    return r;
}
// swap a.rows[32:63] <-> b.rows[0:31]
__device__ __forceinline__ void pl32swap(unsigned &a, unsigned &b) {
#if __has_builtin(__builtin_amdgcn_permlane32_swap)
    auto r = __builtin_amdgcn_permlane32_swap(a, b, false, false);
    a = r[0]; b = r[1];
#else
    asm("v_permlane32_swap_b32 %0, %1" : "+v"(a), "+v"(b));
#endif
}

#define GLL(gp, lp) __builtin_amdgcn_global_load_lds( \
    (const __attribute__((address_space(1))) unsigned int*)(gp), \
    (__attribute__((address_space(3))) unsigned int*)(lp), 16, 0, 0)

// ---------------- merged prep: x fp32->bf16 + 4 weight transpose-converts ----
// One launch replaces 5 (launch-gap elimination: ~13 us/launch measured from
// round-0/1 dispatch-sum vs wall-clock).  Branch is on blockIdx -> block-
// uniform, so the __syncthreads inside the transpose body is safe.
__device__ __forceinline__ void transpose_body(const float* __restrict__ W,
                                               u16* __restrict__ Wt,
                                               int K, int N, int n0, int k0,
                                               int tid, float (*tile)[65]) {
    const int r = tid >> 4, c4 = (tid & 15) * 4;
#pragma unroll
    for (int i = 0; i < 4; i++) {
        float4 v = *(const float4*)(W + (size_t)(k0 + r + i * 16) * N + n0 + c4);
        tile[r + i * 16][c4 + 0] = v.x;
        tile[r + i * 16][c4 + 1] = v.y;
        tile[r + i * 16][c4 + 2] = v.z;
        tile[r + i * 16][c4 + 3] = v.w;
    }
    __syncthreads();
    const int n = tid >> 2, kg = (tid & 3) * 16;
    __align__(16) u16 tmp[16];
#pragma unroll
    for (int j = 0; j < 16; j++) tmp[j] = f2bf(tile[kg + j][n]);
    u16* dst = Wt + (size_t)(n0 + n) * K + k0 + kg;
    *(uint4*)dst = *(const uint4*)tmp;
    *(uint4*)(dst + 8) = *(const uint4*)(tmp + 8);
}

// block ranges: [0,10240) conv; [10240,11840) Wq; [11840,12240) Wk;
// [12240,12640) Wv; [12640,14240) Wo
__global__ __launch_bounds__(256) void prep(const float* __restrict__ x,
                                            u16* __restrict__ xh,
                                            const float* __restrict__ Wq,
                                            const float* __restrict__ Wk,
                                            const float* __restrict__ Wv,
                                            const float* __restrict__ Wo,
                                            u16* __restrict__ Wqkvt,
                                            u16* __restrict__ Wot) {
    __shared__ float tile[64][65];
    const int b = blockIdx.x, tid = threadIdx.x;
    if (b < 10240) {
        int i = (b * 256 + tid) * 4;
        float4 v = *(const float4*)(x + i);
        u16x4 o = { f2bf(v.x), f2bf(v.y), f2bf(v.z), f2bf(v.w) };
        *(u16x4*)(xh + i) = o;
    } else if (b < 11840) {
        int l = b - 10240;
        transpose_body(Wq, Wqkvt, HIDDEN, QH_COLS, (l % 40) * 64, (l / 40) * 64, tid, tile);
    } else if (b < 12240) {
        int l = b - 11840;
        transpose_body(Wk, Wqkvt + (size_t)QH_COLS * HIDDEN, HIDDEN, KV_COLS,
                       (l % 10) * 64, (l / 10) * 64, tid, tile);
    } else if (b < 12640) {
        int l = b - 12240;
        transpose_body(Wv, Wqkvt + (size_t)(QH_COLS + KV_COLS) * HIDDEN, HIDDEN, KV_COLS,
                       (l % 10) * 64, (l / 10) * 64, tid, tile);
    } else {
        int l = b - 12640;
        transpose_body(Wo, Wot, QH_COLS, HIDDEN, (l % 40) * 64, (l / 40) * 64, tid, tile);
    }
}

// ---------------- 256x256 bf16 GEMM, round-5 8-phase schedule (best: 130us) ----
// Reverted verbatim from round 5 (r6's 1-barrier variant regressed 130->137.5).
// 512 threads = 8 waves (2M x 4N), per-wave 128x64 = acc[8][4] 16x16x32 frags.
// BK=64, tiles in pairs (t0->buf0, t1->buf1); LDS 128 KB chunked
// [kc:4][256][8] half-regions (0 bank conflicts, lane-linear GLL).
// Phase = {reads; 1-half stage; barrier; sched_barrier; setprio MFMA16;
//          [vmcnt(6) at ph4/8]; barrier; sched_barrier}.
#define STAGE_HALF(MP, ROFF, T, KH) do { \
    GLL(MP + (T) * 64 + (KH) * 32 + skc * 8,       SM + (ROFF) + skc * 2048 + srow8); \
    GLL(MP + (T) * 64 + (KH) * 32 + (skc + 2) * 8, SM + (ROFF) + (skc + 2) * 2048 + srow8); \
} while (0)

#define MFMA16(IH) \
    __builtin_amdgcn_s_setprio(1); \
    acc[(IH)*4+0][0] = __builtin_amdgcn_mfma_f32_16x16x32_bf16(a0, b0, acc[(IH)*4+0][0], 0, 0, 0); \
    acc[(IH)*4+0][1] = __builtin_amdgcn_mfma_f32_16x16x32_bf16(a0, b1, acc[(IH)*4+0][1], 0, 0, 0); \
    acc[(IH)*4+0][2] = __builtin_amdgcn_mfma_f32_16x16x32_bf16(a0, b2, acc[(IH)*4+0][2], 0, 0, 0); \
    acc[(IH)*4+0][3] = __builtin_amdgcn_mfma_f32_16x16x32_bf16(a0, b3, acc[(IH)*4+0][3], 0, 0, 0); \
    acc[(IH)*4+1][0] = __builtin_amdgcn_mfma_f32_16x16x32_bf16(a1, b0, acc[(IH)*4+1][0], 0, 0, 0); \
    acc[(IH)*4+1][1] = __builtin_amdgcn_mfma_f32_16x16x32_bf16(a1, b1, acc[(IH)*4+1][1], 0, 0, 0); \
    acc[(IH)*4+1][2] = __builtin_amdgcn_mfma_f32_16x16x32_bf16(a1, b2, acc[(IH)*4+1][2], 0, 0, 0); \
    acc[(IH)*4+1][3] = __builtin_amdgcn_mfma_f32_16x16x32_bf16(a1, b3, acc[(IH)*4+1][3], 0, 0, 0); \
    acc[(IH)*4+2][0] = __builtin_amdgcn_mfma_f32_16x16x32_bf16(a2, b0, acc[(IH)*4+2][0], 0, 0, 0); \
    acc[(IH)*4+2][1] = __builtin_amdgcn_mfma_f32_16x16x32_bf16(a2, b1, acc[(IH)*4+2][1], 0, 0, 0); \
    acc[(IH)*4+2][2] = __builtin_amdgcn_mfma_f32_16x16x32_bf16(a2, b2, acc[(IH)*4+2][2], 0, 0, 0); \
    acc[(IH)*4+2][3] = __builtin_amdgcn_mfma_f32_16x16x32_bf16(a2, b3, acc[(IH)*4+2][3], 0, 0, 0); \
    acc[(IH)*4+3][0] = __builtin_amdgcn_mfma_f32_16x16x32_bf16(a3, b0, acc[(IH)*4+3][0], 0, 0, 0); \
    acc[(IH)*4+3][1] = __builtin_amdgcn_mfma_f32_16x16x32_bf16(a3, b1, acc[(IH)*4+3][1], 0, 0, 0); \
    acc[(IH)*4+3][2] = __builtin_amdgcn_mfma_f32_16x16x32_bf16(a3, b2, acc[(IH)*4+3][2], 0, 0, 0); \
    acc[(IH)*4+3][3] = __builtin_amdgcn_mfma_f32_16x16x32_bf16(a3, b3, acc[(IH)*4+3][3], 0, 0, 0); \
    __builtin_amdgcn_s_setprio(0);

#define PHASE(BUFB, KH, IH, RDB, STAGE_STMT, VM_STMT) { \
    const u16* _ar = SM + (BUFB) + (KH) * 8192 + aoff + (IH) * 512; \
    shortx8 a0 = *(const shortx8*)(_ar); \
    shortx8 a1 = *(const shortx8*)(_ar + 128); \
    shortx8 a2 = *(const shortx8*)(_ar + 256); \
    shortx8 a3 = *(const shortx8*)(_ar + 384); \
    if (RDB) { \
        const u16* _br = SM + (BUFB) + (KH) * 8192 + boff; \
        b0 = *(const shortx8*)(_br); \
        b1 = *(const shortx8*)(_br + 128); \
        b2 = *(const shortx8*)(_br + 256); \
        b3 = *(const shortx8*)(_br + 384); \
    } \
    STAGE_STMT; \
    asm volatile("" ::: "memory"); \
    __builtin_amdgcn_s_barrier(); \
    __builtin_amdgcn_sched_barrier(0); \
    MFMA16(IH); \
    VM_STMT; \
    asm volatile("" ::: "memory"); \
    __builtin_amdgcn_s_barrier(); \
    __builtin_amdgcn_sched_barrier(0); \
}

template <typename OutT>
__global__ __launch_bounds__(512, 2) void gemm256(const u16* __restrict__ A,
                                                  const u16* __restrict__ Bt,
                                                  OutT* __restrict__ C,
                                                  int M, int N, int K,
                                                  int nbx) {
    __shared__ __align__(16) u16 SM[65536];
    const int tid = threadIdx.x;
    const int wave = tid >> 6, lane = tid & 63;
    const int m16 = lane & 15, quad = lane >> 4;
    const int wm = wave >> 2, wn = wave & 3;

    // XCD-aware bijective swizzle (nwg is a multiple of 8)
    const int nwg = nbx * (M >> 8);
    const int cpx = nwg >> 3;
    const int bid = (int)blockIdx.x;
    const int swzb = (bid & 7) * cpx + (bid >> 3);
    const int bm = (swzb / nbx) * 256, bn = (swzb % nbx) * 256;

    // staging: thread covers row srow, kc chunks {skc, skc+2} of a half-region
    const int srow = tid & 255, skc = tid >> 8;
    const int srow8 = srow * 8;
    const u16* pA = A  + (size_t)(bm + srow) * K;
    const u16* pB = Bt + (size_t)(bn + srow) * K;

    // fragment read offsets (u16): + BUFB + kh*8192 (+16384 for B) + frag*128
    const int aoff = quad * 2048 + (wm * 128 + m16) * 8;
    const int boff = 16384 + quad * 2048 + (wn * 64 + m16) * 8;

    floatx4 acc[8][4];
#pragma unroll
    for (int i = 0; i < 8; i++)
#pragma unroll
        for (int j = 0; j < 4; j++) acc[i][j] = (floatx4){0.f, 0.f, 0.f, 0.f};

    const int nkt = K >> 6;       // 40 (even, K % 128 == 0)
    const int nit = nkt >> 1;

    // ---- prologue: fully stage tile0 (buf0) then tile1 (buf1), FIFO order ----
    STAGE_HALF(pA, 0,     0, 0);
    STAGE_HALF(pB, 16384, 0, 0);
    STAGE_HALF(pA, 8192,  0, 1);
    STAGE_HALF(pB, 24576, 0, 1);
    STAGE_HALF(pA, 32768, 1, 0);
    STAGE_HALF(pB, 49152, 1, 0);
    STAGE_HALF(pA, 40960, 1, 1);
    STAGE_HALF(pB, 57344, 1, 1);
    asm volatile("s_waitcnt vmcnt(8)" ::: "memory");   // tile 0 landed
    __builtin_amdgcn_s_barrier();

    for (int it = 0; it < nit; ++it) {
        const int t0 = 2 * it, t1 = t0 + 1;
        const bool pf = (it + 1 < nit);
        shortx8 b0, b1, b2, b3;
        // tile t0 (buf0): phases 1-4
        PHASE(0, 0, 0, true,
              { if (it) STAGE_HALF(pA, 40960, t1, 1); }, {});
        PHASE(0, 0, 1, false,
              { if (pf) STAGE_HALF(pB, 16384, t0 + 2, 0); }, {});
        PHASE(0, 1, 0, true,
              { if (pf) STAGE_HALF(pA, 0, t0 + 2, 0); }, {});
        PHASE(0, 1, 1, false,
              { if (pf) STAGE_HALF(pB, 24576, t0 + 2, 1); },
              { if (pf) { asm volatile("s_waitcnt vmcnt(6)" ::: "memory"); }
                else    { asm volatile("s_waitcnt vmcnt(0)" ::: "memory"); } });
        // tile t1 (buf1): phases 5-8
        PHASE(32768, 0, 0, true,
              { if (pf) STAGE_HALF(pA, 8192, t0 + 2, 1); }, {});
        PHASE(32768, 0, 1, false,
              { if (pf) STAGE_HALF(pB, 49152, t1 + 2, 0); }, {});
        PHASE(32768, 1, 0, true,
              { if (pf) STAGE_HALF(pA, 32768, t1 + 2, 0); }, {});
        PHASE(32768, 1, 1, false,
              { if (pf) STAGE_HALF(pB, 57344, t1 + 2, 1); },
              { if (pf) { asm volatile("s_waitcnt vmcnt(6)" ::: "memory"); }
                else    { asm volatile("s_waitcnt vmcnt(0)" ::: "memory"); } });
    }

#pragma unroll
    for (int i = 0; i < 8; i++)
#pragma unroll
        for (int j = 0; j < 4; j++)
#pragma unroll
            for (int p = 0; p < 4; p++) {
                int row = bm + wm * 128 + i * 16 + quad * 4 + p;
                int col = bn + wn * 64 + j * 16 + m16;
                storeC(acc[i][j][p], &C[(size_t)row * N + col]);
            }
}

// ---------------- RoPE, in place on fused qkv rows; Q pre-scaled ----------------
__global__ __launch_bounds__(256) void rope_bf16(__hip_bfloat16* __restrict__ qkv,
                                                 const float* __restrict__ cf,
                                                 const float* __restrict__ sf) {
    int idx = blockIdx.x * 256 + threadIdx.x;
    int d  = idx % 40;
    int t  = idx / 40;
    int hh = t % (NH + NKV);
    int g  = t / (NH + NKV);
    int s  = g & (SEQ - 1);
    float c1 = cf[s * HD + d],      s1 = sf[s * HD + d];
    float c2 = cf[s * HD + d + 40], s2 = sf[s * HD + d + 40];
    const float qsc = (hh < NH) ? (float)(0.11180339887498949 * 1.4426950408889634) : 1.0f;
    __hip_bfloat16* p = (hh < NH) ? (qkv + (size_t)g * QKV_COLS + hh * HD)
                                  : (qkv + (size_t)g * QKV_COLS + QH_COLS + (hh - NH) * HD);
    float x1 = __bfloat162float(p[d]);
    float x2 = __bfloat162float(p[d + 40]);
    p[d]      = __float2bfloat16((x1 * c1 - x2 * s1) * qsc);
    p[d + 40] = __float2bfloat16((x2 * c2 + x1 * s2) * qsc);
}

// ---------------- 32x32 MFMA flash attention, S^T formulation ----------------
// round-0-verified structure + T5 setprio around the MFMA clusters (attn
// blocks are independent, non-lockstep -> the regime where setprio pays).
__device__ __forceinline__ void stage_K(const u16* kg, u16* dst, int wave, int lane) {
#pragma unroll
    for (int t = 0; t < 2; t++) {
        int s = t * 256 + wave * 64 + lane;
        int db = t * 4 + wave;
        GLL(kg + (size_t)lane * QKV_COLS + db * 8, dst + s * 8);
    }
    if (wave < 2) {
        int s = 512 + wave * 64 + lane;
        int db = 8 + wave;
        GLL(kg + (size_t)lane * QKV_COLS + db * 8, dst + s * 8);
    }
}

__device__ __forceinline__ void load_V(const u16* vg, shortx8* vr, int wave, int lane) {
#pragma unroll
    for (int t = 0; t < 2; t++) {
        int db = t * 4 + wave;
        vr[t] = *(const shortx8*)(vg + (size_t)lane * QKV_COLS + db * 8);
    }
    if (wave < 2) vr[2] = *(const shortx8*)(vg + (size_t)lane * QKV_COLS + (8 + wave) * 8);
}

__device__ __forceinline__ void scatter_V(u16* Vs, const shortx8* vr, int wave, int lane) {
    const int kc = lane >> 3, jj = lane & 7;
    u16* base = Vs + kc * 768 + jj;
#pragma unroll
    for (int t = 0; t < 2; t++) {
        int db = t * 4 + wave;
#pragma unroll
        for (int i = 0; i < 8; i++) base[db * 64 + ((i ^ kc) << 3)] = vr[t][i];
    }
    if (wave < 2) {
        int db = 8 + wave;
#pragma unroll
        for (int i = 0; i < 8; i++) base[db * 64 + ((i ^ kc) << 3)] = vr[2][i];
    }
}

__global__ __launch_bounds__(256, 3) void attn_mfma(const u16* __restrict__ qkv,
                                                    u16* __restrict__ ob) {
    __shared__ __align__(16) u16 SM[16384];    // 32 KB
    u16* Kbuf = SM;            // 2 x 5120 u16; also Q staging [128][80] in prologue
    u16* Vs   = SM + 10240;    // 6144 u16 = [8][96][8]

    const int tid  = threadIdx.x;
    const int wave = tid >> 6;
    const int lane = tid & 63;
    const int l31  = lane & 31;
    const int hi   = lane >> 5;

    const int idx = blockIdx.x;                // 1D grid, LPT: qt=15 blocks first
    const int qt  = 15 - (idx >> 6);
    const int hb  = idx & 63;
    const int h   = hb >> 1;
    const int b   = hb & 1;
    const int kvh = h >> 2;
    const int qb  = qt * 128 + wave * 32;      // wave's first query row

    const u16* qgb = qkv + (size_t)(b * SEQ + qt * 128) * QKV_COLS + h * HD;
    const u16* kg0 = qkv + (size_t)(b * SEQ) * QKV_COLS + QH_COLS + kvh * HD;
    const u16* vg0 = qkv + (size_t)(b * SEQ) * QKV_COLS + QH_COLS + KV_COLS + kvh * HD;

    // zero V pad rows (d 80..95 of each kc chunk) -- disjoint from Q staging
    {
        int kc = tid >> 5, o = (tid & 31) * 4;
        *(u16x4*)(Vs + kc * 768 + 640 + o) = (u16x4){0, 0, 0, 0};
    }

    // ---- prologue: stage Q -> SM linear [128][80], read frags to regs ----
#pragma unroll
    for (int t = 0; t < 5; t++) {
        int s = t * 256 + tid;
        int row = s / 10, ch = s % 10;
        GLL(qgb + (size_t)row * QKV_COLS + ch * 8, SM + s * 8);
    }
    __syncthreads();
    shortx8 qf[5];
    {
        const u16* qrow = SM + (wave * 32 + l31) * 80 + hi * 8;
#pragma unroll
        for (int c = 0; c < 5; c++) qf[c] = *(const shortx8*)(qrow + c * 16);
    }
    __syncthreads();   // all waves' Q reads done; SM free for K

    // per-lane PV read bases: V_sub[kc8=2c+hi][(n*32+l31)^kc8][.]
    int vbase[4];
#pragma unroll
    for (int c = 0; c < 4; c++) {
        int k8 = c * 2 + hi;
        vbase[c] = k8 * 768 + ((l31 & 24) + ((l31 & 7) ^ k8)) * 8;
    }
    const u16* kfp = Kbuf + hi * 512 + l31 * 8;   // + cur*5120 + c*1024 + kr*256

    // ---- stage K0 (direct->LDS) and V0 (regs, then scatter) ----
    stage_K(kg0, Kbuf, wave, lane);
    shortx8 vr[3];
    load_V(vg0, vr, wave, lane);
    __syncthreads();                 // K0 in LDS (barrier drains vmcnt)
    scatter_V(Vs, vr, wave, lane);
    __syncthreads();                 // V0 visible

    floatx16 Oacc[3];
#pragma unroll
    for (int n = 0; n < 3; n++)
#pragma unroll
        for (int r = 0; r < 16; r++) Oacc[n][r] = 0.0f;
    float mrow = -1.0e30f, lrow = 0.0f;
    int cur = 0;
    const int nkt = 2 * qt + 2;

    for (int kt = 0; kt < nkt; kt++) {
        const bool last = (kt == nkt - 1);
        if (!last) {   // prefetch kt+1: K direct into other buffer, V into regs
            const u16* kg = kg0 + (size_t)(kt + 1) * 64 * QKV_COLS;
            const u16* vg = vg0 + (size_t)(kt + 1) * 64 * QKV_COLS;
            stage_K(kg, Kbuf + (cur ^ 1) * 5120, wave, lane);
            load_V(vg, vr, wave, lane);
        }

        const bool active = (kt * 64 <= qb + 31);
        if (active) {
            const u16* kp = kfp + cur * 5120;
            const bool kr1   = (kt * 64 + 32 <= qb + 31);
            const bool dmask = (kt * 64 + 63 > qb);
            // S^T = K.Q^T : D[key][query], col = query = l31
            floatx16 S0, S1;
            __builtin_amdgcn_s_setprio(1);
            {
                floatx16 s;
#pragma unroll
                for (int r = 0; r < 16; r++) s[r] = 0.0f;
#pragma unroll
                for (int c = 0; c < 5; c++) {
                    shortx8 kf = *(const shortx8*)(kp + c * 1024);
                    s = __builtin_amdgcn_mfma_f32_32x32x16_bf16(kf, qf[c], s, 0, 0, 0);
                }
                S0 = s;
            }
            if (kr1) {
                floatx16 s;
#pragma unroll
                for (int r = 0; r < 16; r++) s[r] = 0.0f;
#pragma unroll
                for (int c = 0; c < 5; c++) {
                    shortx8 kf = *(const shortx8*)(kp + c * 1024 + 256);
                    s = __builtin_amdgcn_mfma_f32_32x32x16_bf16(kf, qf[c], s, 0, 0, 0);
                }
                S1 = s;
            }
            __builtin_amdgcn_s_setprio(0);
            const int qrel = qb + l31 - kt * 64;
            if (dmask) {
#pragma unroll
                for (int r = 0; r < 16; r++) {
                    int rr = (r & 3) + 8 * (r >> 2) + 4 * hi;
                    if (rr > qrel) S0[r] = -1.0e30f;
                    if (kr1 && (32 + rr) > qrel) S1[r] = -1.0e30f;
                }
            }
            // online softmax (log2 domain), defer-max THR=8
            float mx = mrow;
#pragma unroll
            for (int r = 0; r < 16; r++) mx = fmaxf(mx, S0[r]);
            if (kr1) {
#pragma unroll
                for (int r = 0; r < 16; r++) mx = fmaxf(mx, S1[r]);
            }
            mx = fmaxf(mx, __shfl_xor(mx, 32));
            if (!__all(mx - mrow <= 8.0f)) {
                float alpha = fexp2(mrow - mx);
                lrow *= alpha;
#pragma unroll
                for (int n = 0; n < 3; n++)
#pragma unroll
                    for (int r = 0; r < 16; r++) Oacc[n][r] *= alpha;
                mrow = mx;
            }
            float rsum = 0.0f;
#pragma unroll
            for (int r = 0; r < 16; r++) { float p = fexp2(S0[r] - mrow); rsum += p; S0[r] = p; }
            if (kr1) {
#pragma unroll
                for (int r = 0; r < 16; r++) { float p = fexp2(S1[r] - mrow); rsum += p; S1[r] = p; }
            }
            rsum += __shfl_xor(rsum, 32);
            lrow += rsum;

            // P -> bf16 B-frags in-register; O^T += V^T.P
#pragma unroll
            for (int kr = 0; kr < 2; kr++) {
                if (kr == 1 && !kr1) break;
                floatx16& Sv = (kr == 0) ? S0 : S1;
                unsigned d0[4], d1[4];
#pragma unroll
                for (int m = 0; m < 4; m++) {
                    d0[m] = cvtpk(Sv[4 * m + 0], Sv[4 * m + 1]);
                    d1[m] = cvtpk(Sv[4 * m + 2], Sv[4 * m + 3]);
                }
#pragma unroll
                for (int cb = 0; cb < 2; cb++) {
                    int c = kr * 2 + cb;
                    if (kt * 64 + c * 16 > qb + 31) break;
                    unsigned x0 = d0[2 * cb], y0 = d0[2 * cb + 1];
                    unsigned x1 = d1[2 * cb], y1 = d1[2 * cb + 1];
                    pl32swap(x0, y0);
                    pl32swap(x1, y1);
                    union { unsigned u[4]; shortx8 s8; } pf;
                    pf.u[0] = x0; pf.u[1] = x1; pf.u[2] = y0; pf.u[3] = y1;
                    __builtin_amdgcn_s_setprio(1);
#pragma unroll
                    for (int n = 0; n < 3; n++) {
                        shortx8 vf = *(const shortx8*)(Vs + vbase[c] + n * 256);
                        Oacc[n] = __builtin_amdgcn_mfma_f32_32x32x16_bf16(vf, pf.s8, Oacc[n], 0, 0, 0);
                    }
                    __builtin_amdgcn_s_setprio(0);
                }
            }
        }

        if (last) break;
        __syncthreads();               // all waves done with Vs & Kbuf[cur]; drains kr/vr vmcnt
        scatter_V(Vs, vr, wave, lane); // write V(kt+1)
        cur ^= 1;
        __syncthreads();               // Vs ready
    }

    // epilogue: O[q][d] from O^T tiles; d = n*32 + 8m + 4hi + p
    const float invl = 1.0f / lrow;
    u16* op = ob + (size_t)(b * SEQ + qt * 128 + wave * 32 + l31) * QH_COLS + h * HD + 4 * hi;
#pragma unroll
    for (int n = 0; n < 3; n++) {
        const int mmax = (n == 2) ? 2 : 4;
#pragma unroll
        for (int m = 0; m < mmax; m++) {
            u16x4 o4 = { f2bf(Oacc[n][4 * m + 0] * invl), f2bf(Oacc[n][4 * m + 1] * invl),
                         f2bf(Oacc[n][4 * m + 2] * invl), f2bf(Oacc[n][4 * m + 3] * invl) };
            *(u16x4*)(op + n * 32 + 8 * m) = o4;
        }
    }
}

// ---------------- launch: 5 kernels (was 9) ----------------
extern "C" void kernel_launch(void* const* d_in, const int* in_sizes, int n_in,
                              void* d_out, int out_size, void* d_ws, size_t ws_size,
                              hipStream_t stream) {
    const float* x    = (const float*)d_in[0];
    const float* cf   = (const float*)d_in[1];
    const float* sf   = (const float*)d_in[2];
    const float* Wq   = (const float*)d_in[3];
    const float* Wk   = (const float*)d_in[4];
    const float* Wv   = (const float*)d_in[5];
    const float* Wo   = (const float*)d_in[6];
    float* out = (float*)d_out;

    u16* xh    = (u16*)d_ws;                            // 4096x2560; later reused as obh
    u16* Wqkvt = xh    + (size_t)ROWS * HIDDEN;         // 3840x2560 (fused q|k|v weightsT)
    u16* Wot   = Wqkvt + (size_t)QKV_COLS * HIDDEN;     // 2560x2560
    u16* qkv   = Wot   + (size_t)QH_COLS * HIDDEN;      // 4096x3840 fused
    u16* obh   = xh;                                    // alias: x dead after projections

    prep<<<dim3(14240), dim3(256), 0, stream>>>(x, xh, Wq, Wk, Wv, Wo, Wqkvt, Wot);

    gemm256<u16><<<dim3((QKV_COLS / 256) * (ROWS / 256)), dim3(512), 0, stream>>>(xh, Wqkvt, qkv, ROWS, QKV_COLS, HIDDEN, QKV_COLS / 256);

    rope_bf16<<<(ROWS * (NH + NKV) * 40) / 256, dim3(256), 0, stream>>>((__hip_bfloat16*)qkv, cf, sf);
    attn_mfma<<<dim3(16 * 64), dim3(256), 0, stream>>>(qkv, obh);

    gemm256<float><<<dim3((HIDDEN / 256) * (ROWS / 256)), dim3(512), 0, stream>>>(obh, Wot, out, ROWS, HIDDEN, QH_COLS, HIDDEN / 256);
}

// Round 8
// 451.355 us; speedup vs baseline: 1.0497x; 1.0111x over previous
//
#include <hip/hip_runtime.h>
#include <hip/hip_bf16.h>
#include <math.h>

#define HIDDEN 2560
#define NH 32
#define NKV 8
#define HD 80
#define BATCH 2
#define SEQ 2048
#define QH_COLS (NH*HD)                  // 2560
#define KV_COLS (NKV*HD)                 // 640
#define QKV_COLS (QH_COLS + 2*KV_COLS)   // 3840 fused q|k|v row
#define ROWS (BATCH*SEQ)                 // 4096

typedef __attribute__((ext_vector_type(4))) float floatx4;
typedef __attribute__((ext_vector_type(16))) float floatx16;
typedef __attribute__((ext_vector_type(8))) short shortx8;
typedef __attribute__((ext_vector_type(4))) unsigned short u16x4;
typedef unsigned short u16;

__device__ inline u16 f2bf(float f) { __hip_bfloat16 h = __float2bfloat16(f); return *(u16*)&h; }
__device__ inline int swz(int r) { return (r + (r >> 2)) & 3; }
__device__ inline void storeC(float v, float* p) { *p = v; }
__device__ inline void storeC(float v, u16* p) { *p = f2bf(v); }

#if __has_builtin(__builtin_amdgcn_exp2f)
__device__ inline float fexp2(float x) { return __builtin_amdgcn_exp2f(x); }
#else
__device__ inline float fexp2(float x) { return __expf(x * 0.6931471805599453f); }
#endif

// packed f32x2 -> bf16x2 (low16 = first arg)
__device__ __forceinline__ unsigned cvtpk(float lo, float hi2) {
    unsigned r;
    asm("v_cvt_pk_bf16_f32 %0, %1, %2" : "=v"(r) : "v"(lo), "v"(hi2));
    return r;
}
// swap a.rows[32:63] <-> b.rows[0:31]
__device__ __forceinline__ void pl32swap(unsigned &a, unsigned &b) {
#if __has_builtin(__builtin_amdgcn_permlane32_swap)
    auto r = __builtin_amdgcn_permlane32_swap(a, b, false, false);
    a = r[0]; b = r[1];
#else
    asm("v_permlane32_swap_b32 %0, %1" : "+v"(a), "+v"(b));
#endif
}

#define GLL(gp, lp) __builtin_amdgcn_global_load_lds( \
    (const __attribute__((address_space(1))) unsigned int*)(gp), \
    (__attribute__((address_space(3))) unsigned int*)(lp), 16, 0, 0)

// ---------------- merged prep: x fp32->bf16 + 4 weight transpose-converts ----
__device__ __forceinline__ void transpose_body(const float* __restrict__ W,
                                               u16* __restrict__ Wt,
                                               int K, int N, int n0, int k0,
                                               int tid, float (*tile)[65]) {
    const int r = tid >> 4, c4 = (tid & 15) * 4;
#pragma unroll
    for (int i = 0; i < 4; i++) {
        float4 v = *(const float4*)(W + (size_t)(k0 + r + i * 16) * N + n0 + c4);
        tile[r + i * 16][c4 + 0] = v.x;
        tile[r + i * 16][c4 + 1] = v.y;
        tile[r + i * 16][c4 + 2] = v.z;
        tile[r + i * 16][c4 + 3] = v.w;
    }
    __syncthreads();
    const int n = tid >> 2, kg = (tid & 3) * 16;
    __align__(16) u16 tmp[16];
#pragma unroll
    for (int j = 0; j < 16; j++) tmp[j] = f2bf(tile[kg + j][n]);
    u16* dst = Wt + (size_t)(n0 + n) * K + k0 + kg;
    *(uint4*)dst = *(const uint4*)tmp;
    *(uint4*)(dst + 8) = *(const uint4*)(tmp + 8);
}

// block ranges: [0,10240) conv; [10240,11840) Wq; [11840,12240) Wk;
// [12240,12640) Wv; [12640,14240) Wo
__global__ __launch_bounds__(256) void prep(const float* __restrict__ x,
                                            u16* __restrict__ xh,
                                            const float* __restrict__ Wq,
                                            const float* __restrict__ Wk,
                                            const float* __restrict__ Wv,
                                            const float* __restrict__ Wo,
                                            u16* __restrict__ Wqkvt,
                                            u16* __restrict__ Wot) {
    __shared__ float tile[64][65];
    const int b = blockIdx.x, tid = threadIdx.x;
    if (b < 10240) {
        int i = (b * 256 + tid) * 4;
        float4 v = *(const float4*)(x + i);
        u16x4 o = { f2bf(v.x), f2bf(v.y), f2bf(v.z), f2bf(v.w) };
        *(u16x4*)(xh + i) = o;
    } else if (b < 11840) {
        int l = b - 10240;
        transpose_body(Wq, Wqkvt, HIDDEN, QH_COLS, (l % 40) * 64, (l / 40) * 64, tid, tile);
    } else if (b < 12240) {
        int l = b - 11840;
        transpose_body(Wk, Wqkvt + (size_t)QH_COLS * HIDDEN, HIDDEN, KV_COLS,
                       (l % 10) * 64, (l / 10) * 64, tid, tile);
    } else if (b < 12640) {
        int l = b - 12240;
        transpose_body(Wv, Wqkvt + (size_t)(QH_COLS + KV_COLS) * HIDDEN, HIDDEN, KV_COLS,
                       (l % 10) * 64, (l / 10) * 64, tid, tile);
    } else {
        int l = b - 12640;
        transpose_body(Wo, Wot, QH_COLS, HIDDEN, (l % 40) * 64, (l / 40) * 64, tid, tile);
    }
}

// ---------------- 128x128 bf16 MFMA GEMM (round-1 kernel, verbatim) ----------
// Used for out-proj (M=4096, N=2560): 640 blocks at 2 blocks/CU fills all 256
// CUs with overlap -- measured 103us on this exact shape in round 1, vs ~130us
// for the 256^2 kernel whose 160-block grid leaves 96 CUs idle.
template <typename OutT>
__global__ __launch_bounds__(256) void gemm_mfma(const u16* __restrict__ A,
                                                 const u16* __restrict__ Bt,
                                                 OutT* __restrict__ C,
                                                 int M, int N, int K) {
    __shared__ __align__(16) u16 As[128 * 32];
    __shared__ __align__(16) u16 Bs[128 * 32];
    const int tid = threadIdx.x;
    const int wave = tid >> 6, lane = tid & 63;
    const int m16 = lane & 15, quad = lane >> 4;
    const int wr = wave >> 1, wc = wave & 1;
    const int bm = blockIdx.y * 128, bn = blockIdx.x * 128;

    const u16* gA[2]; const u16* gB[2]; u16* lA[2]; u16* lB[2];
#pragma unroll
    for (int i = 0; i < 2; i++) {
        int c = wave + i * 4;
        int o = c * 1024 + lane * 16;
        int r = o >> 6;
        int s = (o >> 4) & 3;
        int kb = s ^ swz(r);
        gA[i] = A  + (size_t)(bm + r) * K + kb * 8;
        gB[i] = Bt + (size_t)(bn + r) * K + kb * 8;
        lA[i] = As + (o >> 1);
        lB[i] = Bs + (o >> 1);
    }
    int offA[4], offB[4];
#pragma unroll
    for (int i = 0; i < 4; i++) {
        int ra = wr * 64 + i * 16 + m16;
        offA[i] = ra * 32 + (quad ^ swz(ra)) * 8;
        int rb = wc * 64 + i * 16 + m16;
        offB[i] = rb * 32 + (quad ^ swz(rb)) * 8;
    }

    floatx4 acc[4][4];
#pragma unroll
    for (int i = 0; i < 4; i++)
#pragma unroll
        for (int j = 0; j < 4; j++) acc[i][j] = (floatx4){0.f, 0.f, 0.f, 0.f};

    for (int k0 = 0; k0 < K; k0 += 32) {
#pragma unroll
        for (int i = 0; i < 2; i++) {
            GLL(gA[i] + k0, lA[i]);
            GLL(gB[i] + k0, lB[i]);
        }
        __syncthreads();
        shortx8 af[4], bfr[4];
#pragma unroll
        for (int i = 0; i < 4; i++) af[i] = *(const shortx8*)(As + offA[i]);
#pragma unroll
        for (int j = 0; j < 4; j++) bfr[j] = *(const shortx8*)(Bs + offB[j]);
#pragma unroll
        for (int i = 0; i < 4; i++)
#pragma unroll
            for (int j = 0; j < 4; j++)
                acc[i][j] = __builtin_amdgcn_mfma_f32_16x16x32_bf16(af[i], bfr[j], acc[i][j], 0, 0, 0);
        __syncthreads();
    }
#pragma unroll
    for (int i = 0; i < 4; i++)
#pragma unroll
        for (int j = 0; j < 4; j++)
#pragma unroll
            for (int p = 0; p < 4; p++) {
                int row = bm + wr * 64 + i * 16 + quad * 4 + p;
                int col = bn + wc * 64 + j * 16 + m16;
                storeC(acc[i][j][p], &C[(size_t)row * N + col]);
            }
}

// ---------------- 256x256 bf16 GEMM, round-5 8-phase schedule (QKV) ----------
#define STAGE_HALF(MP, ROFF, T, KH) do { \
    GLL(MP + (T) * 64 + (KH) * 32 + skc * 8,       SM + (ROFF) + skc * 2048 + srow8); \
    GLL(MP + (T) * 64 + (KH) * 32 + (skc + 2) * 8, SM + (ROFF) + (skc + 2) * 2048 + srow8); \
} while (0)

#define MFMA16(IH) \
    __builtin_amdgcn_s_setprio(1); \
    acc[(IH)*4+0][0] = __builtin_amdgcn_mfma_f32_16x16x32_bf16(a0, b0, acc[(IH)*4+0][0], 0, 0, 0); \
    acc[(IH)*4+0][1] = __builtin_amdgcn_mfma_f32_16x16x32_bf16(a0, b1, acc[(IH)*4+0][1], 0, 0, 0); \
    acc[(IH)*4+0][2] = __builtin_amdgcn_mfma_f32_16x16x32_bf16(a0, b2, acc[(IH)*4+0][2], 0, 0, 0); \
    acc[(IH)*4+0][3] = __builtin_amdgcn_mfma_f32_16x16x32_bf16(a0, b3, acc[(IH)*4+0][3], 0, 0, 0); \
    acc[(IH)*4+1][0] = __builtin_amdgcn_mfma_f32_16x16x32_bf16(a1, b0, acc[(IH)*4+1][0], 0, 0, 0); \
    acc[(IH)*4+1][1] = __builtin_amdgcn_mfma_f32_16x16x32_bf16(a1, b1, acc[(IH)*4+1][1], 0, 0, 0); \
    acc[(IH)*4+1][2] = __builtin_amdgcn_mfma_f32_16x16x32_bf16(a1, b2, acc[(IH)*4+1][2], 0, 0, 0); \
    acc[(IH)*4+1][3] = __builtin_amdgcn_mfma_f32_16x16x32_bf16(a1, b3, acc[(IH)*4+1][3], 0, 0, 0); \
    acc[(IH)*4+2][0] = __builtin_amdgcn_mfma_f32_16x16x32_bf16(a2, b0, acc[(IH)*4+2][0], 0, 0, 0); \
    acc[(IH)*4+2][1] = __builtin_amdgcn_mfma_f32_16x16x32_bf16(a2, b1, acc[(IH)*4+2][1], 0, 0, 0); \
    acc[(IH)*4+2][2] = __builtin_amdgcn_mfma_f32_16x16x32_bf16(a2, b2, acc[(IH)*4+2][2], 0, 0, 0); \
    acc[(IH)*4+2][3] = __builtin_amdgcn_mfma_f32_16x16x32_bf16(a2, b3, acc[(IH)*4+2][3], 0, 0, 0); \
    acc[(IH)*4+3][0] = __builtin_amdgcn_mfma_f32_16x16x32_bf16(a3, b0, acc[(IH)*4+3][0], 0, 0, 0); \
    acc[(IH)*4+3][1] = __builtin_amdgcn_mfma_f32_16x16x32_bf16(a3, b1, acc[(IH)*4+3][1], 0, 0, 0); \
    acc[(IH)*4+3][2] = __builtin_amdgcn_mfma_f32_16x16x32_bf16(a3, b2, acc[(IH)*4+3][2], 0, 0, 0); \
    acc[(IH)*4+3][3] = __builtin_amdgcn_mfma_f32_16x16x32_bf16(a3, b3, acc[(IH)*4+3][3], 0, 0, 0); \
    __builtin_amdgcn_s_setprio(0);

#define PHASE(BUFB, KH, IH, RDB, STAGE_STMT, VM_STMT) { \
    const u16* _ar = SM + (BUFB) + (KH) * 8192 + aoff + (IH) * 512; \
    shortx8 a0 = *(const shortx8*)(_ar); \
    shortx8 a1 = *(const shortx8*)(_ar + 128); \
    shortx8 a2 = *(const shortx8*)(_ar + 256); \
    shortx8 a3 = *(const shortx8*)(_ar + 384); \
    if (RDB) { \
        const u16* _br = SM + (BUFB) + (KH) * 8192 + boff; \
        b0 = *(const shortx8*)(_br); \
        b1 = *(const shortx8*)(_br + 128); \
        b2 = *(const shortx8*)(_br + 256); \
        b3 = *(const shortx8*)(_br + 384); \
    } \
    STAGE_STMT; \
    asm volatile("" ::: "memory"); \
    __builtin_amdgcn_s_barrier(); \
    __builtin_amdgcn_sched_barrier(0); \
    MFMA16(IH); \
    VM_STMT; \
    asm volatile("" ::: "memory"); \
    __builtin_amdgcn_s_barrier(); \
    __builtin_amdgcn_sched_barrier(0); \
}

template <typename OutT>
__global__ __launch_bounds__(512, 2) void gemm256(const u16* __restrict__ A,
                                                  const u16* __restrict__ Bt,
                                                  OutT* __restrict__ C,
                                                  int M, int N, int K,
                                                  int nbx) {
    __shared__ __align__(16) u16 SM[65536];
    const int tid = threadIdx.x;
    const int wave = tid >> 6, lane = tid & 63;
    const int m16 = lane & 15, quad = lane >> 4;
    const int wm = wave >> 2, wn = wave & 3;

    // XCD-aware bijective swizzle (nwg is a multiple of 8)
    const int nwg = nbx * (M >> 8);
    const int cpx = nwg >> 3;
    const int bid = (int)blockIdx.x;
    const int swzb = (bid & 7) * cpx + (bid >> 3);
    const int bm = (swzb / nbx) * 256, bn = (swzb % nbx) * 256;

    // staging: thread covers row srow, kc chunks {skc, skc+2} of a half-region
    const int srow = tid & 255, skc = tid >> 8;
    const int srow8 = srow * 8;
    const u16* pA = A  + (size_t)(bm + srow) * K;
    const u16* pB = Bt + (size_t)(bn + srow) * K;

    // fragment read offsets (u16): + BUFB + kh*8192 (+16384 for B) + frag*128
    const int aoff = quad * 2048 + (wm * 128 + m16) * 8;
    const int boff = 16384 + quad * 2048 + (wn * 64 + m16) * 8;

    floatx4 acc[8][4];
#pragma unroll
    for (int i = 0; i < 8; i++)
#pragma unroll
        for (int j = 0; j < 4; j++) acc[i][j] = (floatx4){0.f, 0.f, 0.f, 0.f};

    const int nkt = K >> 6;       // 40 (even, K % 128 == 0)
    const int nit = nkt >> 1;

    // ---- prologue: fully stage tile0 (buf0) then tile1 (buf1), FIFO order ----
    STAGE_HALF(pA, 0,     0, 0);
    STAGE_HALF(pB, 16384, 0, 0);
    STAGE_HALF(pA, 8192,  0, 1);
    STAGE_HALF(pB, 24576, 0, 1);
    STAGE_HALF(pA, 32768, 1, 0);
    STAGE_HALF(pB, 49152, 1, 0);
    STAGE_HALF(pA, 40960, 1, 1);
    STAGE_HALF(pB, 57344, 1, 1);
    asm volatile("s_waitcnt vmcnt(8)" ::: "memory");   // tile 0 landed
    __builtin_amdgcn_s_barrier();

    for (int it = 0; it < nit; ++it) {
        const int t0 = 2 * it, t1 = t0 + 1;
        const bool pf = (it + 1 < nit);
        shortx8 b0, b1, b2, b3;
        // tile t0 (buf0): phases 1-4
        PHASE(0, 0, 0, true,
              { if (it) STAGE_HALF(pA, 40960, t1, 1); }, {});
        PHASE(0, 0, 1, false,
              { if (pf) STAGE_HALF(pB, 16384, t0 + 2, 0); }, {});
        PHASE(0, 1, 0, true,
              { if (pf) STAGE_HALF(pA, 0, t0 + 2, 0); }, {});
        PHASE(0, 1, 1, false,
              { if (pf) STAGE_HALF(pB, 24576, t0 + 2, 1); },
              { if (pf) { asm volatile("s_waitcnt vmcnt(6)" ::: "memory"); }
                else    { asm volatile("s_waitcnt vmcnt(0)" ::: "memory"); } });
        // tile t1 (buf1): phases 5-8
        PHASE(32768, 0, 0, true,
              { if (pf) STAGE_HALF(pA, 8192, t0 + 2, 1); }, {});
        PHASE(32768, 0, 1, false,
              { if (pf) STAGE_HALF(pB, 49152, t1 + 2, 0); }, {});
        PHASE(32768, 1, 0, true,
              { if (pf) STAGE_HALF(pA, 32768, t1 + 2, 0); }, {});
        PHASE(32768, 1, 1, false,
              { if (pf) STAGE_HALF(pB, 57344, t1 + 2, 1); },
              { if (pf) { asm volatile("s_waitcnt vmcnt(6)" ::: "memory"); }
                else    { asm volatile("s_waitcnt vmcnt(0)" ::: "memory"); } });
    }

#pragma unroll
    for (int i = 0; i < 8; i++)
#pragma unroll
        for (int j = 0; j < 4; j++)
#pragma unroll
            for (int p = 0; p < 4; p++) {
                int row = bm + wm * 128 + i * 16 + quad * 4 + p;
                int col = bn + wn * 64 + j * 16 + m16;
                storeC(acc[i][j][p], &C[(size_t)row * N + col]);
            }
}

// ---------------- RoPE, in place on fused qkv rows; Q pre-scaled ----------------
__global__ __launch_bounds__(256) void rope_bf16(__hip_bfloat16* __restrict__ qkv,
                                                 const float* __restrict__ cf,
                                                 const float* __restrict__ sf) {
    int idx = blockIdx.x * 256 + threadIdx.x;
    int d  = idx % 40;
    int t  = idx / 40;
    int hh = t % (NH + NKV);
    int g  = t / (NH + NKV);
    int s  = g & (SEQ - 1);
    float c1 = cf[s * HD + d],      s1 = sf[s * HD + d];
    float c2 = cf[s * HD + d + 40], s2 = sf[s * HD + d + 40];
    const float qsc = (hh < NH) ? (float)(0.11180339887498949 * 1.4426950408889634) : 1.0f;
    __hip_bfloat16* p = (hh < NH) ? (qkv + (size_t)g * QKV_COLS + hh * HD)
                                  : (qkv + (size_t)g * QKV_COLS + QH_COLS + (hh - NH) * HD);
    float x1 = __bfloat162float(p[d]);
    float x2 = __bfloat162float(p[d + 40]);
    p[d]      = __float2bfloat16((x1 * c1 - x2 * s1) * qsc);
    p[d + 40] = __float2bfloat16((x2 * c2 + x1 * s2) * qsc);
}

// ---------------- 32x32 MFMA flash attention, S^T formulation ----------------
__device__ __forceinline__ void stage_K(const u16* kg, u16* dst, int wave, int lane) {
#pragma unroll
    for (int t = 0; t < 2; t++) {
        int s = t * 256 + wave * 64 + lane;
        int db = t * 4 + wave;
        GLL(kg + (size_t)lane * QKV_COLS + db * 8, dst + s * 8);
    }
    if (wave < 2) {
        int s = 512 + wave * 64 + lane;
        int db = 8 + wave;
        GLL(kg + (size_t)lane * QKV_COLS + db * 8, dst + s * 8);
    }
}

__device__ __forceinline__ void load_V(const u16* vg, shortx8* vr, int wave, int lane) {
#pragma unroll
    for (int t = 0; t < 2; t++) {
        int db = t * 4 + wave;
        vr[t] = *(const shortx8*)(vg + (size_t)lane * QKV_COLS + db * 8);
    }
    if (wave < 2) vr[2] = *(const shortx8*)(vg + (size_t)lane * QKV_COLS + (8 + wave) * 8);
}

__device__ __forceinline__ void scatter_V(u16* Vs, const shortx8* vr, int wave, int lane) {
    const int kc = lane >> 3, jj = lane & 7;
    u16* base = Vs + kc * 768 + jj;
#pragma unroll
    for (int t = 0; t < 2; t++) {
        int db = t * 4 + wave;
#pragma unroll
        for (int i = 0; i < 8; i++) base[db * 64 + ((i ^ kc) << 3)] = vr[t][i];
    }
    if (wave < 2) {
        int db = 8 + wave;
#pragma unroll
        for (int i = 0; i < 8; i++) base[db * 64 + ((i ^ kc) << 3)] = vr[2][i];
    }
}

__global__ __launch_bounds__(256, 3) void attn_mfma(const u16* __restrict__ qkv,
                                                    u16* __restrict__ ob) {
    __shared__ __align__(16) u16 SM[16384];    // 32 KB
    u16* Kbuf = SM;            // 2 x 5120 u16; also Q staging [128][80] in prologue
    u16* Vs   = SM + 10240;    // 6144 u16 = [8][96][8]

    const int tid  = threadIdx.x;
    const int wave = tid >> 6;
    const int lane = tid & 63;
    const int l31  = lane & 31;
    const int hi   = lane >> 5;

    const int idx = blockIdx.x;                // 1D grid, LPT: qt=15 blocks first
    const int qt  = 15 - (idx >> 6);
    const int hb  = idx & 63;
    const int h   = hb >> 1;
    const int b   = hb & 1;
    const int kvh = h >> 2;
    const int qb  = qt * 128 + wave * 32;      // wave's first query row

    const u16* qgb = qkv + (size_t)(b * SEQ + qt * 128) * QKV_COLS + h * HD;
    const u16* kg0 = qkv + (size_t)(b * SEQ) * QKV_COLS + QH_COLS + kvh * HD;
    const u16* vg0 = qkv + (size_t)(b * SEQ) * QKV_COLS + QH_COLS + KV_COLS + kvh * HD;

    // zero V pad rows (d 80..95 of each kc chunk) -- disjoint from Q staging
    {
        int kc = tid >> 5, o = (tid & 31) * 4;
        *(u16x4*)(Vs + kc * 768 + 640 + o) = (u16x4){0, 0, 0, 0};
    }

    // ---- prologue: stage Q -> SM linear [128][80], read frags to regs ----
#pragma unroll
    for (int t = 0; t < 5; t++) {
        int s = t * 256 + tid;
        int row = s / 10, ch = s % 10;
        GLL(qgb + (size_t)row * QKV_COLS + ch * 8, SM + s * 8);
    }
    __syncthreads();
    shortx8 qf[5];
    {
        const u16* qrow = SM + (wave * 32 + l31) * 80 + hi * 8;
#pragma unroll
        for (int c = 0; c < 5; c++) qf[c] = *(const shortx8*)(qrow + c * 16);
    }
    __syncthreads();   // all waves' Q reads done; SM free for K

    // per-lane PV read bases: V_sub[kc8=2c+hi][(n*32+l31)^kc8][.]
    int vbase[4];
#pragma unroll
    for (int c = 0; c < 4; c++) {
        int k8 = c * 2 + hi;
        vbase[c] = k8 * 768 + ((l31 & 24) + ((l31 & 7) ^ k8)) * 8;
    }
    const u16* kfp = Kbuf + hi * 512 + l31 * 8;   // + cur*5120 + c*1024 + kr*256

    // ---- stage K0 (direct->LDS) and V0 (regs, then scatter) ----
    stage_K(kg0, Kbuf, wave, lane);
    shortx8 vr[3];
    load_V(vg0, vr, wave, lane);
    __syncthreads();                 // K0 in LDS (barrier drains vmcnt)
    scatter_V(Vs, vr, wave, lane);
    __syncthreads();                 // V0 visible

    floatx16 Oacc[3];
#pragma unroll
    for (int n = 0; n < 3; n++)
#pragma unroll
        for (int r = 0; r < 16; r++) Oacc[n][r] = 0.0f;
    float mrow = -1.0e30f, lrow = 0.0f;
    int cur = 0;
    const int nkt = 2 * qt + 2;

    for (int kt = 0; kt < nkt; kt++) {
        const bool last = (kt == nkt - 1);
        if (!last) {   // prefetch kt+1: K direct into other buffer, V into regs
            const u16* kg = kg0 + (size_t)(kt + 1) * 64 * QKV_COLS;
            const u16* vg = vg0 + (size_t)(kt + 1) * 64 * QKV_COLS;
            stage_K(kg, Kbuf + (cur ^ 1) * 5120, wave, lane);
            load_V(vg, vr, wave, lane);
        }

        const bool active = (kt * 64 <= qb + 31);
        if (active) {
            const u16* kp = kfp + cur * 5120;
            const bool kr1   = (kt * 64 + 32 <= qb + 31);
            const bool dmask = (kt * 64 + 63 > qb);
            // S^T = K.Q^T : D[key][query], col = query = l31
            floatx16 S0, S1;
            __builtin_amdgcn_s_setprio(1);
            {
                floatx16 s;
#pragma unroll
                for (int r = 0; r < 16; r++) s[r] = 0.0f;
#pragma unroll
                for (int c = 0; c < 5; c++) {
                    shortx8 kf = *(const shortx8*)(kp + c * 1024);
                    s = __builtin_amdgcn_mfma_f32_32x32x16_bf16(kf, qf[c], s, 0, 0, 0);
                }
                S0 = s;
            }
            if (kr1) {
                floatx16 s;
#pragma unroll
                for (int r = 0; r < 16; r++) s[r] = 0.0f;
#pragma unroll
                for (int c = 0; c < 5; c++) {
                    shortx8 kf = *(const shortx8*)(kp + c * 1024 + 256);
                    s = __builtin_amdgcn_mfma_f32_32x32x16_bf16(kf, qf[c], s, 0, 0, 0);
                }
                S1 = s;
            }
            __builtin_amdgcn_s_setprio(0);
            const int qrel = qb + l31 - kt * 64;
            if (dmask) {
#pragma unroll
                for (int r = 0; r < 16; r++) {
                    int rr = (r & 3) + 8 * (r >> 2) + 4 * hi;
                    if (rr > qrel) S0[r] = -1.0e30f;
                    if (kr1 && (32 + rr) > qrel) S1[r] = -1.0e30f;
                }
            }
            // online softmax (log2 domain), defer-max THR=8
            float mx = mrow;
#pragma unroll
            for (int r = 0; r < 16; r++) mx = fmaxf(mx, S0[r]);
            if (kr1) {
#pragma unroll
                for (int r = 0; r < 16; r++) mx = fmaxf(mx, S1[r]);
            }
            mx = fmaxf(mx, __shfl_xor(mx, 32));
            if (!__all(mx - mrow <= 8.0f)) {
                float alpha = fexp2(mrow - mx);
                lrow *= alpha;
#pragma unroll
                for (int n = 0; n < 3; n++)
#pragma unroll
                    for (int r = 0; r < 16; r++) Oacc[n][r] *= alpha;
                mrow = mx;
            }
            float rsum = 0.0f;
#pragma unroll
            for (int r = 0; r < 16; r++) { float p = fexp2(S0[r] - mrow); rsum += p; S0[r] = p; }
            if (kr1) {
#pragma unroll
                for (int r = 0; r < 16; r++) { float p = fexp2(S1[r] - mrow); rsum += p; S1[r] = p; }
            }
            rsum += __shfl_xor(rsum, 32);
            lrow += rsum;

            // P -> bf16 B-frags in-register; O^T += V^T.P
#pragma unroll
            for (int kr = 0; kr < 2; kr++) {
                if (kr == 1 && !kr1) break;
                floatx16& Sv = (kr == 0) ? S0 : S1;
                unsigned d0[4], d1[4];
#pragma unroll
                for (int m = 0; m < 4; m++) {
                    d0[m] = cvtpk(Sv[4 * m + 0], Sv[4 * m + 1]);
                    d1[m] = cvtpk(Sv[4 * m + 2], Sv[4 * m + 3]);
                }
#pragma unroll
                for (int cb = 0; cb < 2; cb++) {
                    int c = kr * 2 + cb;
                    if (kt * 64 + c * 16 > qb + 31) break;
                    unsigned x0 = d0[2 * cb], y0 = d0[2 * cb + 1];
                    unsigned x1 = d1[2 * cb], y1 = d1[2 * cb + 1];
                    pl32swap(x0, y0);
                    pl32swap(x1, y1);
                    union { unsigned u[4]; shortx8 s8; } pf;
                    pf.u[0] = x0; pf.u[1] = x1; pf.u[2] = y0; pf.u[3] = y1;
                    __builtin_amdgcn_s_setprio(1);
#pragma unroll
                    for (int n = 0; n < 3; n++) {
                        shortx8 vf = *(const shortx8*)(Vs + vbase[c] + n * 256);
                        Oacc[n] = __builtin_amdgcn_mfma_f32_32x32x16_bf16(vf, pf.s8, Oacc[n], 0, 0, 0);
                    }
                    __builtin_amdgcn_s_setprio(0);
                }
            }
        }

        if (last) break;
        __syncthreads();               // all waves done with Vs & Kbuf[cur]; drains kr/vr vmcnt
        scatter_V(Vs, vr, wave, lane); // write V(kt+1)
        cur ^= 1;
        __syncthreads();               // Vs ready
    }

    // epilogue: O[q][d] from O^T tiles; d = n*32 + 8m + 4hi + p
    const float invl = 1.0f / lrow;
    u16* op = ob + (size_t)(b * SEQ + qt * 128 + wave * 32 + l31) * QH_COLS + h * HD + 4 * hi;
#pragma unroll
    for (int n = 0; n < 3; n++) {
        const int mmax = (n == 2) ? 2 : 4;
#pragma unroll
        for (int m = 0; m < mmax; m++) {
            u16x4 o4 = { f2bf(Oacc[n][4 * m + 0] * invl), f2bf(Oacc[n][4 * m + 1] * invl),
                         f2bf(Oacc[n][4 * m + 2] * invl), f2bf(Oacc[n][4 * m + 3] * invl) };
            *(u16x4*)(op + n * 32 + 8 * m) = o4;
        }
    }
}

// ---------------- launch: 5 kernels ----------------
extern "C" void kernel_launch(void* const* d_in, const int* in_sizes, int n_in,
                              void* d_out, int out_size, void* d_ws, size_t ws_size,
                              hipStream_t stream) {
    const float* x    = (const float*)d_in[0];
    const float* cf   = (const float*)d_in[1];
    const float* sf   = (const float*)d_in[2];
    const float* Wq   = (const float*)d_in[3];
    const float* Wk   = (const float*)d_in[4];
    const float* Wv   = (const float*)d_in[5];
    const float* Wo   = (const float*)d_in[6];
    float* out = (float*)d_out;

    u16* xh    = (u16*)d_ws;                            // 4096x2560; later reused as obh
    u16* Wqkvt = xh    + (size_t)ROWS * HIDDEN;         // 3840x2560 (fused q|k|v weightsT)
    u16* Wot   = Wqkvt + (size_t)QKV_COLS * HIDDEN;     // 2560x2560
    u16* qkv   = Wot   + (size_t)QH_COLS * HIDDEN;      // 4096x3840 fused
    u16* obh   = xh;                                    // alias: x dead after projections

    prep<<<dim3(14240), dim3(256), 0, stream>>>(x, xh, Wq, Wk, Wv, Wo, Wqkvt, Wot);

    gemm256<u16><<<dim3((QKV_COLS / 256) * (ROWS / 256)), dim3(512), 0, stream>>>(xh, Wqkvt, qkv, ROWS, QKV_COLS, HIDDEN, QKV_COLS / 256);

    rope_bf16<<<(ROWS * (NH + NKV) * 40) / 256, dim3(256), 0, stream>>>((__hip_bfloat16*)qkv, cf, sf);
    attn_mfma<<<dim3(16 * 64), dim3(256), 0, stream>>>(qkv, obh);

    gemm_mfma<float><<<dim3(HIDDEN / 128, ROWS / 128), dim3(256), 0, stream>>>(obh, Wot, out, ROWS, HIDDEN, QH_COLS);
}